// Round 10
// baseline (174.721 us; speedup 1.0000x reference)
//
#include <hip/hip_runtime.h>
#include <hip/hip_fp16.h>
#include <cmath>

#define N_NODES 50000
#define N_EDGES 800000
#define D 64
#define N_REL 8

#define NODES_PER_BLK 32
#define TN 16                       // nodes per block in tables_kernel
#define MAXDEG 64                   // ELL row pad; P(deg>64 | Poisson(16)) ~ 1e-20
#define NSEG 8                      // dst segments == XCD count
#define SEG_DIV 6250                // 50000 / 8

typedef __attribute__((ext_vector_type(8))) short bf16x8;
typedef __attribute__((ext_vector_type(4))) float f32x4;
union FragU { uint4 u; bf16x8 b; };

// float -> bf16 bits, round-to-nearest-even
static __device__ __forceinline__ unsigned f2bf(float f) {
    unsigned u = __float_as_uint(f);
    return (u + 0x7FFFu + ((u >> 16) & 1u)) >> 16;
}
#define BFLO(u) __uint_as_float((u) << 16)
#define BFHI(u) __uint_as_float((u) & 0xFFFF0000u)

// ---------------------------------------------------------------------------
// K0: w[r*128 + j] = sum_k W_r[r][j][k]; zero cnt (200 KB).
// ---------------------------------------------------------------------------
__global__ void wprep_kernel(const float* __restrict__ W_r, float* __restrict__ w,
                             int* __restrict__ cnt) {
    int t = blockIdx.x * blockDim.x + threadIdx.x;
    if (t < N_REL * 2 * D) {
        const float* p = W_r + (size_t)t * D;
        float s = 0.0f;
#pragma unroll
        for (int k = 0; k < D; ++k) s += p[k];
        w[t] = s;
    }
    for (int i = t; i < N_NODES; i += gridDim.x * blockDim.x)
        cnt[i] = 0;
}

// ---------------------------------------------------------------------------
// K1: logit tables (tall-skinny GEMM) + xb side-product (packed bf16 x).
// ---------------------------------------------------------------------------
__global__ __launch_bounds__(256) void tables_kernel(
    const float* __restrict__ x, const float* __restrict__ w,
    float* __restrict__ Dn, float* __restrict__ Sr,
    unsigned short* __restrict__ xb)
{
    __shared__ float xs[TN][68];
    __shared__ float ws[16][68];

    int tid = threadIdx.x;
    int n0  = blockIdx.x * TN;

    for (int i = tid; i < 16 * 64; i += 256)
        ws[i >> 6][i & 63] = w[i];
    for (int i = tid; i < TN * 64; i += 256) {
        int n = n0 + (i >> 6);
        xs[i >> 6][i & 63] = (n < N_NODES) ? x[(size_t)n * D + (i & 63)] : 0.f;
    }
    __syncthreads();

    for (int i = tid; i < TN * 64; i += 256) {
        int n = n0 + (i >> 6);
        if (n < N_NODES) xb[(size_t)n0 * D + i] = (unsigned short)f2bf(xs[i >> 6][i & 63]);
    }

    int q = tid & 15, nl = tid >> 4;
    float acc = 0.f;
#pragma unroll
    for (int k = 0; k < 64; k += 4) {
        float4 a = *(const float4*)&xs[nl][k];
        float4 b = *(const float4*)&ws[q][k];
        acc += a.x * b.x + a.y * b.y + a.z * b.z + a.w * b.w;
    }
    int n = n0 + nl;
    if (n < N_NODES) {
        int r = q >> 1;
        if ((q & 1) == 0) Dn[n * 8 + r] = acc;
        else              Sr[n * 8 + r] = acc;
    }
}

// ---------------------------------------------------------------------------
// K2: XCD-partitioned ELL scatter, 1 edge/thread -- EXACT R4 structure,
// best measured (47.6us). R9's unsegmented variant regressed to 55us:
// without dst-segmentation the 12.8MB epack write-set spans all 8 XCD L2s
// (WRITE 39->48.6MB). Both variants sit at ~90MB of random-64B-line traffic
// at ~2TB/s effective -- segmented minimizes total traffic.
// Loads issued unconditionally & pinned before the filter; rank atomic
// (50K addresses) issued before the Dn/Sr gathers so latencies overlap.
// ---------------------------------------------------------------------------
__global__ __launch_bounds__(256) void scatter_kernel(
    const int* __restrict__ src, const int* __restrict__ dst,
    const int* __restrict__ rel,
    int* __restrict__ cnt,
    const float* __restrict__ Dn, const float* __restrict__ Sr,
    unsigned int* __restrict__ epack) {
    int seg   = blockIdx.x & (NSEG - 1);
    int chunk = blockIdx.x >> 3;
    int e = chunk * 256 + threadIdx.x;
    if (e >= N_EDGES) return;

    // issue all three coalesced loads before any dependent use
    int d = dst[e];
    int s = src[e];
    int r = rel[e];
    // pin: forbid sinking src/rel loads into the survivor branch
    asm volatile("" :: "v"(d), "v"(s), "v"(r));

    if ((unsigned)d / SEG_DIV != (unsigned)seg) return;   // magic-mul div

    // rank is independent of gate: issue the atomic first, overlap gathers
    int rank = atomicAdd(&cnt[d], 1);

    float logit = Dn[d * 8 + r] + Sr[s * 8 + r];
    float gate = 1.0f / (1.0f + __expf(-logit));
    if (rank < MAXDEG) {
        unsigned pv = ((unsigned)__half_as_ushort(__float2half_rn(gate)) << 16)
                    | (unsigned)s;
        epack[(size_t)d * MAXDEG + rank] = pv;
    }
}

// ---------------------------------------------------------------------------
// K3: FUSED aggregation + linear layer.
// Phase A (R10): 8 nodes per wave, but the per-node gather loops are JAMMED
// into one base-loop over mmax (wave-uniform max degree of the 8). The
// zero-pad trick (slots >= m carry gl=0/ol=0 -> row-0 hot line, contribute
// exactly 0) makes this branch-free: each base round issues 16 INDEPENDENT
// gathers (8 nodes x 2) instead of 2. Serial gather depth ~16 -> ~4 rounds.
// All arrays statically indexed via full unroll (stay in VGPRs).
// Phase B: [32x128]@[128x64] bf16 GEMM via v_mfma_f32_16x16x32_bf16
// (confirmed correct in R9; VALUBusy win vs scalar).
// ---------------------------------------------------------------------------
__global__ __launch_bounds__(256) void agglin_kernel(
    const unsigned short* __restrict__ xb,
    const unsigned int* __restrict__ xbu,   // same buffer as xb, uint view
    const int*   __restrict__ cnt,
    const unsigned int* __restrict__ epack,
    const float* __restrict__ W_lin,
    const float* __restrict__ b_lin,
    float* __restrict__ out)
{
    __shared__ unsigned int W2[64][68];
    __shared__ unsigned int c2[NODES_PER_BLK][68];
    __shared__ float b_lds[64];

    int tid  = threadIdx.x;
    int n0   = blockIdx.x * NODES_PER_BLK;
    int lane = tid & 63;
    int wv   = tid >> 6;              // wave 0..3

    // ---- staging of W2 / bias / x-half of c2 ----
    for (int i = tid; i < 64 * 64; i += 256) {
        int j = i >> 6, kp = i & 63;
        float2 wvv = *(const float2*)&W_lin[j * 128 + kp * 2];
        W2[j][kp] = f2bf(wvv.x) | (f2bf(wvv.y) << 16);
    }
    if (tid < 64) b_lds[tid] = b_lin[tid];

    for (int i = tid; i < NODES_PER_BLK * 32; i += 256) {
        int nl = i >> 5, kp = i & 31;
        int n  = n0 + nl;
        c2[nl][kp] = (n < N_NODES) ? xbu[(size_t)n * 32 + kp] : 0u;
    }

    // ---- Phase A: aggregate 8 nodes per wave, jammed gather loop ----
    int nbase = n0 + wv * 8;

    int      degv[8], mm[8];
    unsigned ev[8];
#pragma unroll
    for (int i = 0; i < 8; ++i) {
        int n = nbase + i;
        degv[i] = (n < N_NODES) ? cnt[n] : 0;
    }
#pragma unroll
    for (int i = 0; i < 8; ++i) {
        int n = nbase + i;
        ev[i] = (n < N_NODES) ? epack[(size_t)n * MAXDEG + lane] : 0u;
    }

    int sub = lane >> 4;        // edge slot group 0..3
    int q   = lane & 15;
    int q4  = q * 4;            // dims q4..q4+3

    int mmax = 0;
    float gl[8]; int ol[8];
#pragma unroll
    for (int i = 0; i < 8; ++i) {
        mm[i] = (degv[i] < MAXDEG) ? degv[i] : MAXDEG;
        mmax  = (mm[i] > mmax) ? mm[i] : mmax;
        unsigned e_m = (lane < mm[i]) ? ev[i] : 0u;  // zero pad: contributes 0
        gl[i] = __half2float(__ushort_as_half((unsigned short)(e_m >> 16)));
        ol[i] = (int)(e_m & 0xFFFFu) * D;
    }

    float ax[8], ay[8], az[8], aw[8];
#pragma unroll
    for (int i = 0; i < 8; ++i) { ax[i] = 0.f; ay[i] = 0.f; az[i] = 0.f; aw[i] = 0.f; }

    for (int base = 0; base < mmax; base += 8) {
#pragma unroll
        for (int i = 0; i < 8; ++i) {
            float g0 = __shfl(gl[i], base + sub, 64);
            int   o0 = __shfl(ol[i], base + sub, 64);
            float g1 = __shfl(gl[i], base + 4 + sub, 64);
            int   o1 = __shfl(ol[i], base + 4 + sub, 64);
            uint2 u0 = *(const uint2*)&xb[(size_t)o0 + q4];
            uint2 u1 = *(const uint2*)&xb[(size_t)o1 + q4];
            ax[i] += g0 * BFLO(u0.x) + g1 * BFLO(u1.x);
            ay[i] += g0 * BFHI(u0.x) + g1 * BFHI(u1.x);
            az[i] += g0 * BFLO(u0.y) + g1 * BFLO(u1.y);
            aw[i] += g0 * BFHI(u0.y) + g1 * BFHI(u1.y);
        }
    }

#pragma unroll
    for (int i = 0; i < 8; ++i) {
#pragma unroll
        for (int off = 16; off <= 32; off <<= 1) {
            ax[i] += __shfl_xor(ax[i], off, 64);
            ay[i] += __shfl_xor(ay[i], off, 64);
            az[i] += __shfl_xor(az[i], off, 64);
            aw[i] += __shfl_xor(aw[i], off, 64);
        }
        if (sub == 0) {
            float inv = 1.0f / fmaxf((float)degv[i], 1.0f);
            int nl = wv * 8 + i;
            c2[nl][32 + 2 * q]     = f2bf(ax[i] * inv) | (f2bf(ay[i] * inv) << 16);
            c2[nl][32 + 2 * q + 1] = f2bf(az[i] * inv) | (f2bf(aw[i] * inv) << 16);
        }
    }
    __syncthreads();

    // ---- Phase B: out = leaky_relu([x, agg] @ W_lin^T + b) via MFMA ----
    // wave wv: M-tile = wv&1 (16 nodes), N-tiles = (wv>>1) and (wv>>1)+2.
    int mtile = wv & 1;
    int nt0   = wv >> 1;
    int lrow  = lane & 15;
    int kgrp  = lane >> 4;

    float bias0 = b_lds[nt0 * 16 + lrow];
    float bias1 = b_lds[(nt0 + 2) * 16 + lrow];
    f32x4 acc0 = {bias0, bias0, bias0, bias0};
    f32x4 acc1 = {bias1, bias1, bias1, bias1};

#pragma unroll
    for (int ks = 0; ks < 4; ++ks) {
        int cb = ks * 16 + kgrp * 4;
        FragU a, b0, b1;
        a.u  = *(const uint4*)&c2[mtile * 16 + lrow][cb];
        b0.u = *(const uint4*)&W2[nt0 * 16 + lrow][cb];
        b1.u = *(const uint4*)&W2[(nt0 + 2) * 16 + lrow][cb];
        acc0 = __builtin_amdgcn_mfma_f32_16x16x32_bf16(a.b, b0.b, acc0, 0, 0, 0);
        acc1 = __builtin_amdgcn_mfma_f32_16x16x32_bf16(a.b, b1.b, acc1, 0, 0, 0);
    }

#pragma unroll
    for (int i = 0; i < 4; ++i) {
        int node = n0 + mtile * 16 + kgrp * 4 + i;
        if (node < N_NODES) {
            float v0 = acc0[i]; v0 = (v0 > 0.f) ? v0 : 0.01f * v0;
            float v1 = acc1[i]; v1 = (v1 > 0.f) ? v1 : 0.01f * v1;
            out[(size_t)node * D + nt0 * 16 + lrow]       = v0;
            out[(size_t)node * D + (nt0 + 2) * 16 + lrow] = v1;
        }
    }
}

// ---------------------------------------------------------------------------
extern "C" void kernel_launch(void* const* d_in, const int* in_sizes, int n_in,
                              void* d_out, int out_size, void* d_ws, size_t ws_size,
                              hipStream_t stream) {
    const float* x     = (const float*)d_in[0];
    const int*   src   = (const int*)  d_in[1];
    const int*   dst   = (const int*)  d_in[2];
    const int*   rel   = (const int*)  d_in[3];
    const float* W_r   = (const float*)d_in[4];
    const float* W_lin = (const float*)d_in[5];
    const float* b_lin = (const float*)d_in[6];
    float* out = (float*)d_out;

    char* p = (char*)d_ws;
    float*  w       = (float*)p;                p += 4096;
    float*  Dn      = (float*)p;                p += (size_t)N_NODES * 8 * 4;       // 1.6 MB
    float*  Sr      = (float*)p;                p += (size_t)N_NODES * 8 * 4;       // 1.6 MB
    int*    cnt     = (int*)p;                  p += 256 * 1024;                    // 200 KB used
    unsigned int* epack = (unsigned int*)p;     p += (size_t)N_NODES * MAXDEG * 4;  // 12.8 MB
    unsigned short* xb = (unsigned short*)p;    p += (size_t)N_NODES * D * 2;       // 6.4 MB

    wprep_kernel<<<512, 256, 0, stream>>>(W_r, w, cnt);
    tables_kernel<<<(N_NODES + TN - 1) / TN, 256, 0, stream>>>(x, w, Dn, Sr, xb);
    scatter_kernel<<<NSEG * ((N_EDGES + 255) / 256), 256, 0, stream>>>(
        src, dst, rel, cnt, Dn, Sr, epack);
    agglin_kernel<<<(N_NODES + NODES_PER_BLK - 1) / NODES_PER_BLK, 256, 0, stream>>>(
        xb, (const unsigned int*)xb, cnt, epack, W_lin, b_lin, out);
}

// Round 12
// 160.714 us; speedup vs baseline: 1.0872x; 1.0872x over previous
//
#include <hip/hip_runtime.h>
#include <hip/hip_fp16.h>
#include <cmath>

#define N_NODES 50000
#define N_EDGES 800000
#define D 64
#define N_REL 8

#define NODES_PER_BLK 32
#define TN 16                       // nodes per block in tables_kernel
#define MAXDEG 64                   // ELL row pad; P(deg>64 | Poisson(16)) ~ 1e-20
#define NSEG 8                      // dst segments == XCD count
#define SEG_DIV 6250                // 50000 / 8

typedef __attribute__((ext_vector_type(8))) short bf16x8;
typedef __attribute__((ext_vector_type(4))) float f32x4;
union FragU { uint4 u; bf16x8 b; };

// float -> bf16 bits, round-to-nearest-even
static __device__ __forceinline__ unsigned f2bf(float f) {
    unsigned u = __float_as_uint(f);
    return (u + 0x7FFFu + ((u >> 16) & 1u)) >> 16;
}
#define BFLO(u) __uint_as_float((u) << 16)
#define BFHI(u) __uint_as_float((u) & 0xFFFF0000u)

// ---------------------------------------------------------------------------
// K0: w[r*128 + j] = sum_k W_r[r][j][k]; pack W_lin -> bf16x2 W2g ONCE
// (R11: was re-done per-block in agglin = 50MB reads + 13M f2bf kernel-wide);
// zero cnt (200 KB).
// ---------------------------------------------------------------------------
__global__ void wprep_kernel(const float* __restrict__ W_r, float* __restrict__ w,
                             const float* __restrict__ W_lin,
                             unsigned int* __restrict__ W2g,
                             int* __restrict__ cnt) {
    int t = blockIdx.x * blockDim.x + threadIdx.x;
    if (t < N_REL * 2 * D) {
        const float* p = W_r + (size_t)t * D;
        float s = 0.0f;
#pragma unroll
        for (int k = 0; k < D; ++k) s += p[k];
        w[t] = s;
    }
    if (t < 64 * 64) {   // j = t>>6, kp = t&63
        float2 wv = *(const float2*)&W_lin[(t >> 6) * 128 + (t & 63) * 2];
        W2g[t] = f2bf(wv.x) | (f2bf(wv.y) << 16);
    }
    for (int i = t; i < N_NODES; i += gridDim.x * blockDim.x)
        cnt[i] = 0;
}

// ---------------------------------------------------------------------------
// K1: logit tables (tall-skinny GEMM) + xb side-product (packed bf16 x).
// ---------------------------------------------------------------------------
__global__ __launch_bounds__(256) void tables_kernel(
    const float* __restrict__ x, const float* __restrict__ w,
    float* __restrict__ Dn, float* __restrict__ Sr,
    unsigned short* __restrict__ xb)
{
    __shared__ float xs[TN][68];
    __shared__ float ws[16][68];

    int tid = threadIdx.x;
    int n0  = blockIdx.x * TN;

    for (int i = tid; i < 16 * 64; i += 256)
        ws[i >> 6][i & 63] = w[i];
    for (int i = tid; i < TN * 64; i += 256) {
        int n = n0 + (i >> 6);
        xs[i >> 6][i & 63] = (n < N_NODES) ? x[(size_t)n * D + (i & 63)] : 0.f;
    }
    __syncthreads();

    for (int i = tid; i < TN * 64; i += 256) {
        int n = n0 + (i >> 6);
        if (n < N_NODES) xb[(size_t)n0 * D + i] = (unsigned short)f2bf(xs[i >> 6][i & 63]);
    }

    int q = tid & 15, nl = tid >> 4;
    float acc = 0.f;
#pragma unroll
    for (int k = 0; k < 64; k += 4) {
        float4 a = *(const float4*)&xs[nl][k];
        float4 b = *(const float4*)&ws[q][k];
        acc += a.x * b.x + a.y * b.y + a.z * b.z + a.w * b.w;
    }
    int n = n0 + nl;
    if (n < N_NODES) {
        int r = q >> 1;
        if ((q & 1) == 0) Dn[n * 8 + r] = acc;
        else              Sr[n * 8 + r] = acc;
    }
}

// ---------------------------------------------------------------------------
// K2: XCD-partitioned ELL scatter, 1 edge/thread -- EXACT R4 structure,
// best measured (47.6us; R9 unsegmented = 55us, R7 split = 59us).
// ---------------------------------------------------------------------------
__global__ __launch_bounds__(256) void scatter_kernel(
    const int* __restrict__ src, const int* __restrict__ dst,
    const int* __restrict__ rel,
    int* __restrict__ cnt,
    const float* __restrict__ Dn, const float* __restrict__ Sr,
    unsigned int* __restrict__ epack) {
    int seg   = blockIdx.x & (NSEG - 1);
    int chunk = blockIdx.x >> 3;
    int e = chunk * 256 + threadIdx.x;
    if (e >= N_EDGES) return;

    // issue all three coalesced loads before any dependent use
    int d = dst[e];
    int s = src[e];
    int r = rel[e];
    // pin: forbid sinking src/rel loads into the survivor branch
    asm volatile("" :: "v"(d), "v"(s), "v"(r));

    if ((unsigned)d / SEG_DIV != (unsigned)seg) return;   // magic-mul div

    // rank is independent of gate: issue the atomic first, overlap gathers
    int rank = atomicAdd(&cnt[d], 1);

    float logit = Dn[d * 8 + r] + Sr[s * 8 + r];
    float gate = 1.0f / (1.0f + __expf(-logit));
    if (rank < MAXDEG) {
        unsigned pv = ((unsigned)__half_as_ushort(__float2half_rn(gate)) << 16)
                    | (unsigned)s;
        epack[(size_t)d * MAXDEG + rank] = pv;
    }
}

// ---------------------------------------------------------------------------
// K3: FUSED aggregation + linear layer.
// Phase A: EXACT R9 per-node loop (R10's jammed variant regressed: VGPR
// 40->72 dropped occupancy 36->22% and mmax wasted ~1.5x gathers). Per
// wave 8 nodes; cnt + ELL rows loaded up-front; R3 shfl distribution;
// branch-free inner loop (pad slots contribute 0).
// Staging (R11): W2 is a pure uint4 LDS copy from pre-packed W2g -- no
// f2bf, half the bytes.
// Phase B: [32x128]@[128x64] bf16 GEMM via v_mfma_f32_16x16x32_bf16.
// ---------------------------------------------------------------------------
__global__ __launch_bounds__(256) void agglin_kernel(
    const unsigned short* __restrict__ xb,
    const unsigned int* __restrict__ xbu,   // same buffer as xb, uint view
    const int*   __restrict__ cnt,
    const unsigned int* __restrict__ epack,
    const unsigned int* __restrict__ W2g,
    const float* __restrict__ b_lin,
    float* __restrict__ out)
{
    __shared__ unsigned int W2[64][68];
    __shared__ unsigned int c2[NODES_PER_BLK][68];
    __shared__ float b_lds[64];

    int tid  = threadIdx.x;
    int n0   = blockIdx.x * NODES_PER_BLK;
    int lane = tid & 63;
    int wv   = tid >> 6;              // wave 0..3

    // ---- staging: W2 (uint4 copy of pre-packed weights), bias, x-half of c2
    for (int i = tid; i < 64 * 16; i += 256) {
        int j = i >> 4, k4 = (i & 15) * 4;
        *(uint4*)&W2[j][k4] = *(const uint4*)&W2g[j * 64 + k4];
    }
    if (tid < 64) b_lds[tid] = b_lin[tid];

    for (int i = tid; i < NODES_PER_BLK * 32; i += 256) {
        int nl = i >> 5, kp = i & 31;
        int n  = n0 + nl;
        c2[nl][kp] = (n < N_NODES) ? xbu[(size_t)n * 32 + kp] : 0u;
    }

    // ---- Phase A: aggregate 8 nodes per wave (R9 structure) ----
    int nbase = n0 + wv * 8;

    int      degv[8];
    unsigned ev[8];
#pragma unroll
    for (int i = 0; i < 8; ++i) {
        int n = nbase + i;
        degv[i] = (n < N_NODES) ? cnt[n] : 0;
    }
#pragma unroll
    for (int i = 0; i < 8; ++i) {
        int n = nbase + i;
        ev[i] = (n < N_NODES) ? epack[(size_t)n * MAXDEG + lane] : 0u;
    }

    int sub = lane >> 4;        // edge slot group 0..3
    int q   = lane & 15;
    int q4  = q * 4;            // dims q4..q4+3

#pragma unroll
    for (int i = 0; i < 8; ++i) {
        int m = (degv[i] < MAXDEG) ? degv[i] : MAXDEG;
        unsigned e_m = (lane < m) ? ev[i] : 0u;   // zero pad slots: contribute 0
        float gl = __half2float(__ushort_as_half((unsigned short)(e_m >> 16)));
        int   ol = (int)(e_m & 0xFFFFu) * D;

        float ax = 0.f, ay = 0.f, az = 0.f, aw = 0.f;
        for (int base = 0; base < m; base += 8) {
            int e0 = base + sub;
            int e1 = base + 4 + sub;
            float g0 = __shfl(gl, e0, 64);
            int   o0 = __shfl(ol, e0, 64);
            float g1 = __shfl(gl, e1, 64);
            int   o1 = __shfl(ol, e1, 64);
            uint2 u0 = *(const uint2*)&xb[(size_t)o0 + q4];
            uint2 u1 = *(const uint2*)&xb[(size_t)o1 + q4];
            ax += g0 * BFLO(u0.x) + g1 * BFLO(u1.x);
            ay += g0 * BFHI(u0.x) + g1 * BFHI(u1.x);
            az += g0 * BFLO(u0.y) + g1 * BFLO(u1.y);
            aw += g0 * BFHI(u0.y) + g1 * BFHI(u1.y);
        }

#pragma unroll
        for (int off = 16; off <= 32; off <<= 1) {
            ax += __shfl_xor(ax, off, 64);
            ay += __shfl_xor(ay, off, 64);
            az += __shfl_xor(az, off, 64);
            aw += __shfl_xor(aw, off, 64);
        }

        if (sub == 0) {
            float inv = 1.0f / fmaxf((float)degv[i], 1.0f);
            int nl = wv * 8 + i;
            c2[nl][32 + 2 * q]     = f2bf(ax * inv) | (f2bf(ay * inv) << 16);
            c2[nl][32 + 2 * q + 1] = f2bf(az * inv) | (f2bf(aw * inv) << 16);
        }
    }
    __syncthreads();

    // ---- Phase B: out = leaky_relu([x, agg] @ W_lin^T + b) via MFMA ----
    // wave wv: M-tile = wv&1 (16 nodes), N-tiles = (wv>>1) and (wv>>1)+2.
    int mtile = wv & 1;
    int nt0   = wv >> 1;
    int lrow  = lane & 15;
    int kgrp  = lane >> 4;

    float bias0 = b_lds[nt0 * 16 + lrow];
    float bias1 = b_lds[(nt0 + 2) * 16 + lrow];
    f32x4 acc0 = {bias0, bias0, bias0, bias0};
    f32x4 acc1 = {bias1, bias1, bias1, bias1};

#pragma unroll
    for (int ks = 0; ks < 4; ++ks) {
        int cb = ks * 16 + kgrp * 4;
        FragU a, b0, b1;
        a.u  = *(const uint4*)&c2[mtile * 16 + lrow][cb];
        b0.u = *(const uint4*)&W2[nt0 * 16 + lrow][cb];
        b1.u = *(const uint4*)&W2[(nt0 + 2) * 16 + lrow][cb];
        acc0 = __builtin_amdgcn_mfma_f32_16x16x32_bf16(a.b, b0.b, acc0, 0, 0, 0);
        acc1 = __builtin_amdgcn_mfma_f32_16x16x32_bf16(a.b, b1.b, acc1, 0, 0, 0);
    }

#pragma unroll
    for (int i = 0; i < 4; ++i) {
        int node = n0 + mtile * 16 + kgrp * 4 + i;
        if (node < N_NODES) {
            float v0 = acc0[i]; v0 = (v0 > 0.f) ? v0 : 0.01f * v0;
            float v1 = acc1[i]; v1 = (v1 > 0.f) ? v1 : 0.01f * v1;
            out[(size_t)node * D + nt0 * 16 + lrow]       = v0;
            out[(size_t)node * D + (nt0 + 2) * 16 + lrow] = v1;
        }
    }
}

// ---------------------------------------------------------------------------
extern "C" void kernel_launch(void* const* d_in, const int* in_sizes, int n_in,
                              void* d_out, int out_size, void* d_ws, size_t ws_size,
                              hipStream_t stream) {
    const float* x     = (const float*)d_in[0];
    const int*   src   = (const int*)  d_in[1];
    const int*   dst   = (const int*)  d_in[2];
    const int*   rel   = (const int*)  d_in[3];
    const float* W_r   = (const float*)d_in[4];
    const float* W_lin = (const float*)d_in[5];
    const float* b_lin = (const float*)d_in[6];
    float* out = (float*)d_out;

    char* p = (char*)d_ws;
    float*  w       = (float*)p;                p += 4096;
    unsigned int* W2g = (unsigned int*)p;       p += 64 * 64 * 4;                   // 16 KB
    float*  Dn      = (float*)p;                p += (size_t)N_NODES * 8 * 4;       // 1.6 MB
    float*  Sr      = (float*)p;                p += (size_t)N_NODES * 8 * 4;       // 1.6 MB
    int*    cnt     = (int*)p;                  p += 256 * 1024;                    // 200 KB used
    unsigned int* epack = (unsigned int*)p;     p += (size_t)N_NODES * MAXDEG * 4;  // 12.8 MB
    unsigned short* xb = (unsigned short*)p;    p += (size_t)N_NODES * D * 2;       // 6.4 MB

    wprep_kernel<<<512, 256, 0, stream>>>(W_r, w, W_lin, W2g, cnt);
    tables_kernel<<<(N_NODES + TN - 1) / TN, 256, 0, stream>>>(x, w, Dn, Sr, xb);
    scatter_kernel<<<NSEG * ((N_EDGES + 255) / 256), 256, 0, stream>>>(
        src, dst, rel, cnt, Dn, Sr, epack);
    agglin_kernel<<<(N_NODES + NODES_PER_BLK - 1) / NODES_PER_BLK, 256, 0, stream>>>(
        xb, (const unsigned int*)xb, cnt, epack, W2g, b_lin, out);
}